// Round 8
// baseline (774.380 us; speedup 1.0000x reference)
//
#include <hip/hip_runtime.h>

// Round 8: 1024 thr (16 waves = 4/SIMD), one block/CU, 64 rows (2 chunks).
// Wave specialization by chunk: side A (waves 0-7) does MM_A in alpha phases
// and GATE_A in beta phases; side B mirrored. So every phase has 2 MFMA waves
// + 2 gate(trans/VALU) waves per SIMD -> pipe overlap across waves instead of
// serial within a wave. B-weights staged ONCE in LDS (128 KB, dynamic smem,
// XOR-swizzled); regs per wave ~60 persistent -> no spills at 128-reg budget.
// POS reads h from LDS in the phase AFTER its gate writes it (race-free
// window: h_X(t) overwritten only 2 phases later). c in f32 regs; decoder
// pos-path folded into Whh_d (pure LSTM); obs-fold exact f32 on VALU.

#define OBS_LEN 8
#define PRED_LEN 12
#define BATCH 131072
#define HID 128
#define NZ 512
#define KWT 128

typedef float f32x4 __attribute__((ext_vector_type(4)));
typedef float f32x2 __attribute__((ext_vector_type(2)));
typedef unsigned short u16x8 __attribute__((ext_vector_type(8)));
typedef __bf16 bf16x8 __attribute__((ext_vector_type(8)));

#define K2F 1.4426950408889634f   // log2(e)

static __device__ __forceinline__ unsigned short cvt1(float f) {
  __bf16 b = (__bf16)f;
  return __builtin_bit_cast(unsigned short, b);
}
static __device__ __forceinline__ float bf2f(unsigned short h) {
  return __uint_as_float(((unsigned int)h) << 16);
}

// ---------------- prep (r7-verified, unchanged) ----------------
// Permuted col c: cg=c>>6, gate=(c>>4)&3, cl=c&15; unit=cg*16+cl; n=gate*128+unit.
__global__ void prep_weights(const float* __restrict__ We,   const float* __restrict__ be,
                             const float* __restrict__ Wih_e,const float* __restrict__ Whh_e,
                             const float* __restrict__ b_e,
                             const float* __restrict__ Wd,   const float* __restrict__ bd,
                             const float* __restrict__ Wih_d,const float* __restrict__ Whh_d,
                             const float* __restrict__ b_d,
                             const float* __restrict__ Wo,   const float* __restrict__ bo,
                             unsigned short* __restrict__ wt_enc,
                             unsigned short* __restrict__ wt_dec,
                             float* __restrict__ aux_enc, float* __restrict__ aux_dec) {
  const int c = blockIdx.x & (NZ - 1);
  const bool dec = blockIdx.x >= NZ;
  const int cg = c >> 6, gate = (c >> 4) & 3, cl = c & 15;
  const int unit = cg * 16 + cl;
  const int n = gate * HID + unit;

  const float* Whh = dec ? Whh_d : Whh_e;
  const float* Wih = dec ? Wih_d : Wih_e;
  const float* Wem = dec ? Wd : We;
  const float* bem = dec ? bd : be;
  const float* bl  = dec ? b_d : b_e;
  unsigned short* wt = dec ? wt_dec : wt_enc;

  float wx = 0.f, wy = 0.f;
  for (int e = 0; e < HID; ++e) {
    wx += Wem[e] * Wih[e * NZ + n];
    wy += Wem[HID + e] * Wih[e * NZ + n];
  }
  for (int k = threadIdx.x; k < KWT; k += 64) {
    float v = Whh[k * NZ + n];
    if (dec) v += Wo[k * 2] * wx + Wo[k * 2 + 1] * wy;
    wt[c * KWT + k] = cvt1(v);
  }
  if (threadIdx.x == 0) {
    float bb = bl[n];
    for (int e = 0; e < HID; ++e) bb += bem[e] * Wih[e * NZ + n];
    if (!dec) {
      aux_enc[n] = wx; aux_enc[NZ + n] = wy; aux_enc[2 * NZ + n] = bb;
    } else {
      aux_dec[n] = bb + bo[0] * wx + bo[1] * wy;
    }
  }
}

// ---------------- main fused kernel ----------------
// MFMA 16x16x32 bf16 (HW-verified r1-r7):
//  A/B frag: row/col = lane&15, k = 32kc + (lane>>4)*8 + j
//  C/D: col = lane&15, row = (lane>>4)*4 + reg
// LDS swizzle (r7-verified): elem(r,k) = r*128 + (((k>>3)^(r&7))<<3) + (k&7)

#define EXP4(D, S)                                                             \
  { f32x4 _s = (S);                                                            \
    D[0] = __builtin_amdgcn_exp2f(_s[0]); D[1] = __builtin_amdgcn_exp2f(_s[1]);\
    D[2] = __builtin_amdgcn_exp2f(_s[2]); D[3] = __builtin_amdgcn_exp2f(_s[3]); }
#define RCP4(D, S)                                                             \
  { f32x4 _r = (S);                                                            \
    D[0] = __builtin_amdgcn_rcpf(_r[0]); D[1] = __builtin_amdgcn_rcpf(_r[1]);  \
    D[2] = __builtin_amdgcn_rcpf(_r[2]); D[3] = __builtin_amdgcn_rcpf(_r[3]); }

#define INITC()                                                                \
  { _Pragma("unroll")                                                          \
    for (int m = 0; m < 2; ++m) {                                              \
      _Pragma("unroll")                                                        \
      for (int g = 0; g < 4; ++g)                                              \
        acc[m][g] = (f32x4){bb[g], bb[g], bb[g], bb[g]};                       \
    } }

// full K=128 matmul for own chunk: A 8 + B 16 ds_read_b128, 32 MFMA
#define MMLDS()                                                                \
  { INITC()                                                                    \
    _Pragma("unroll")                                                          \
    for (int kc = 0; kc < 4; ++kc) {                                           \
      const int gsh = (((kc * 4 + l4) ^ (l15 & 7)) << 3);                      \
      u16x8 _a0 = *(const u16x8*)&Al[abase + l15 * 128 + gsh];                 \
      u16x8 _a1 = *(const u16x8*)&Al[abase + (16 + l15) * 128 + gsh];          \
      _Pragma("unroll")                                                        \
      for (int nt = 0; nt < 4; ++nt) {                                         \
        u16x8 _bf =                                                            \
            *(const u16x8*)&Bl[(cg * 64 + nt * 16 + l15) * 128 + gsh];         \
        acc[0][nt] = __builtin_amdgcn_mfma_f32_16x16x32_bf16(                  \
            __builtin_bit_cast(bf16x8, _a0), __builtin_bit_cast(bf16x8, _bf),  \
            acc[0][nt], 0, 0, 0);                                              \
        acc[1][nt] = __builtin_amdgcn_mfma_f32_16x16x32_bf16(                  \
            __builtin_bit_cast(bf16x8, _a1), __builtin_bit_cast(bf16x8, _bf),  \
            acc[1][nt], 0, 0, 0);                                              \
      } } }

// gate for own chunk; FOLD literal (encoder obs-embed fold)
#define GATEC(FOLD)                                                            \
  { _Pragma("unroll")                                                          \
    for (int m = 0; m < 2; ++m) {                                              \
      f32x4 g_zi = acc[m][0], g_zf = acc[m][1];                                \
      f32x4 g_zg = acc[m][2], g_zo = acc[m][3];                                \
      if (FOLD) {                                                              \
        f32x4 g_px = m ? px1 : px0, g_py = m ? py1 : py0;                      \
        g_zi += g_px * wx[0] + g_py * wy[0];                                   \
        g_zf += g_px * wx[1] + g_py * wy[1];                                   \
        g_zg += g_px * wx[2] + g_py * wy[2];                                   \
        g_zo += g_px * wx[3] + g_py * wy[3];                                   \
      }                                                                        \
      f32x4 g_eB, g_eA, g_eG, g_eO;                                            \
      EXP4(g_eB, g_zi * (-K2F)) EXP4(g_eA, g_zf * (-K2F))                      \
      EXP4(g_eG, g_zg * (-2.f * K2F)) EXP4(g_eO, g_zo * (-K2F))                \
      f32x4 g_a1 = 1.f + g_eA, g_b1 = 1.f + g_eB, g_g1 = 1.f + g_eG;           \
      f32x4 g_bg = g_b1 * g_g1;                                                \
      f32x4 g_rd; RCP4(g_rd, g_a1 * g_bg)                                      \
      f32x4 g_cv = (crr[m] * g_bg + (1.f - g_eG) * g_a1) * g_rd;               \
      crr[m] = g_cv;                                                           \
      f32x4 g_eC; EXP4(g_eC, g_cv * (-2.f * K2F))                              \
      f32x4 g_rh; RCP4(g_rh, (1.f + g_eO) * (1.f + g_eC))                      \
      f32x4 g_hv = (1.f - g_eC) * g_rh;                                        \
      const int g_R0 = 16 * m + l4 * 4;                                        \
      _Pragma("unroll")                                                        \
      for (int r = 0; r < 4; ++r)                                              \
        Al[abase + (g_R0 + r) * 128 + ((uh ^ ((g_R0 + r) & 7)) << 3) + ul] =   \
            cvt1(g_hv[r]);                                                     \
    } }

// pos = h @ Wo + bo for chunk CH (this side's 512 threads; st = side-local tid)
#define POSC(S, CH)                                                            \
  { const int pp_r = st >> 4, pp_q = st & 15;                                  \
    u16x8 pp_h = *(const u16x8*)&Al[(CH)*4096 + pp_r * 128 +                   \
                                    ((pp_q ^ (pp_r & 7)) << 3)];               \
    const float* pp_w = WoL + pp_q * 16;                                       \
    f32x4 pp_w0 = *(const f32x4*)pp_w;                                         \
    f32x4 pp_w1 = *(const f32x4*)(pp_w + 4);                                   \
    f32x4 pp_w2 = *(const f32x4*)(pp_w + 8);                                   \
    f32x4 pp_w3 = *(const f32x4*)(pp_w + 12);                                  \
    f32x2 pp_s = (f32x2){0.f, 0.f};                                            \
    pp_s += bf2f(pp_h[0]) * (f32x2){pp_w0[0], pp_w0[1]};                       \
    pp_s += bf2f(pp_h[1]) * (f32x2){pp_w0[2], pp_w0[3]};                       \
    pp_s += bf2f(pp_h[2]) * (f32x2){pp_w1[0], pp_w1[1]};                       \
    pp_s += bf2f(pp_h[3]) * (f32x2){pp_w1[2], pp_w1[3]};                       \
    pp_s += bf2f(pp_h[4]) * (f32x2){pp_w2[0], pp_w2[1]};                       \
    pp_s += bf2f(pp_h[5]) * (f32x2){pp_w2[2], pp_w2[3]};                       \
    pp_s += bf2f(pp_h[6]) * (f32x2){pp_w3[0], pp_w3[1]};                       \
    pp_s += bf2f(pp_h[7]) * (f32x2){pp_w3[2], pp_w3[3]};                       \
    pp_s[0] += __shfl_xor(pp_s[0], 1); pp_s[1] += __shfl_xor(pp_s[1], 1);      \
    pp_s[0] += __shfl_xor(pp_s[0], 2); pp_s[1] += __shfl_xor(pp_s[1], 2);      \
    pp_s[0] += __shfl_xor(pp_s[0], 4); pp_s[1] += __shfl_xor(pp_s[1], 4);      \
    pp_s[0] += __shfl_xor(pp_s[0], 8); pp_s[1] += __shfl_xor(pp_s[1], 8);      \
    if (pp_q == 0) {                                                           \
      float2 pp_o; pp_o.x = pp_s[0] + bo0; pp_o.y = pp_s[1] + bo1;             \
      ((float2*)out)[(size_t)(S)*BATCH + row0 + (CH)*32 + pp_r] = pp_o;        \
    } }

// obs rows for own chunk's gate fold
#define LOADP(T)                                                               \
  { const float* lp_b =                                                        \
        obs + 2 * ((size_t)(T)*BATCH + row0 + side * 32 + l4 * 4);             \
    f32x4 lp_q0 = *(const f32x4*)lp_b;                                         \
    f32x4 lp_q1 = *(const f32x4*)(lp_b + 4);                                   \
    f32x4 lp_q2 = *(const f32x4*)(lp_b + 32);                                  \
    f32x4 lp_q3 = *(const f32x4*)(lp_b + 36);                                  \
    px0 = (f32x4){lp_q0[0], lp_q0[2], lp_q1[0], lp_q1[2]};                     \
    py0 = (f32x4){lp_q0[1], lp_q0[3], lp_q1[1], lp_q1[3]};                     \
    px1 = (f32x4){lp_q2[0], lp_q2[2], lp_q3[0], lp_q3[2]};                     \
    py1 = (f32x4){lp_q2[1], lp_q2[3], lp_q3[1], lp_q3[3]}; }

#define SMEM_BYTES (((NZ * 128) + (2 * 32 * 128)) * 2 + 128 * 2 * 4)

__global__ __launch_bounds__(1024, 1) void lstm_fused(
    const float* __restrict__ obs,
    const unsigned short* __restrict__ wt_enc,
    const unsigned short* __restrict__ wt_dec,
    const float* __restrict__ aux_enc, const float* __restrict__ aux_dec,
    const float* __restrict__ Wo, const float* __restrict__ bo,
    float* __restrict__ out) {
  extern __shared__ unsigned short smem_u16[];
  unsigned short* Bl = smem_u16;                       // [512][128] swizzled
  unsigned short* Al = smem_u16 + NZ * 128;            // [2][32][128] swizzled
  float* WoL = (float*)(smem_u16 + NZ * 128 + 2 * 32 * 128);  // [128][2]

  const int tid = threadIdx.x;
  const int lane = tid & 63;
  const int wn = tid >> 6;            // 0..15
  const int side = wn >> 3;           // 0 = chunk A, 1 = chunk B
  const int cg = wn & 7;              // col-group: units [16cg,16cg+16)
  const int st = tid & 511;           // side-local tid
  const int l15 = lane & 15;
  const int l4 = lane >> 4;
  const int row0 = blockIdx.x * 64;
  const int u = cg * 16 + l15, uh = u >> 3, ul = u & 7;
  const int abase = side * 4096;      // own chunk's A-tile (u16 elems)
  const float bo0 = bo[0], bo1 = bo[1];

  // ---- P0: stage B_enc (swizzled), zero A-tiles, WoL, aux ----
  {
    const int sc = wn * 32 + (lane >> 1);
    const unsigned short* ssrc = wt_enc + sc * KWT + (lane & 1) * 64;
    unsigned short* sdst = Bl + sc * 128;
#pragma unroll
    for (int j = 0; j < 8; ++j) {
      const int gw = (lane & 1) * 8 + j;
      *(u16x8*)&sdst[(gw ^ (sc & 7)) << 3] = *(const u16x8*)(ssrc + j * 8);
    }
  }
  *(u16x8*)&Al[tid * 8] = (u16x8){0, 0, 0, 0, 0, 0, 0, 0};  // 1024*8 = 16 KB
  if (tid < HID) { WoL[tid * 2] = Wo[tid * 2]; WoL[tid * 2 + 1] = Wo[tid * 2 + 1]; }

  float wx[4], wy[4], bb[4];
#pragma unroll
  for (int g = 0; g < 4; ++g) {
    wx[g] = aux_enc[g * HID + u];
    wy[g] = aux_enc[NZ + g * HID + u];
    bb[g] = aux_enc[2 * NZ + g * HID + u];
  }

  f32x4 acc[2][4];
  f32x4 crr[2];
  crr[0] = crr[1] = (f32x4){0.f, 0.f, 0.f, 0.f};
  f32x4 px0, py0, px1, py1;
  __syncthreads();

  // ---- encoder t = 0..7 ----
#pragma unroll 1
  for (int t = 0; t < OBS_LEN; ++t) {
    // alpha(t): A: MM_A(t) ; B: GATE_B(t-1)
    if (side == 0) { MMLDS() }
    else if (t > 0) { LOADP(t - 1) GATEC(1) }
    __syncthreads();
    // beta(t): B: MM_B(t) ; A: GATE_A(t)
    if (side == 1) { MMLDS() }
    else { LOADP(t) GATEC(1) }
    __syncthreads();
  }

  // ---- PT: A stages B_dec ; B does GATE_B(7). Both: dec state ----
  if (side == 0) {
    const int dc = cg * 64 + lane;
    const unsigned short* dsrc = wt_dec + dc * KWT;
    unsigned short* ddst = Bl + dc * 128;
#pragma unroll
    for (int j = 0; j < 16; ++j)
      *(u16x8*)&ddst[(j ^ (dc & 7)) << 3] = *(const u16x8*)(dsrc + j * 8);
  } else {
    LOADP(OBS_LEN - 1) GATEC(1)   // GATE_B(7)
  }
  crr[0] = crr[1] = (f32x4){0.f, 0.f, 0.f, 0.f};
#pragma unroll
  for (int g = 0; g < 4; ++g) bb[g] = aux_dec[g * HID + u];
  __syncthreads();

  // ---- dalpha(1): A: MM_A^dec(1) ; B: POSC_A(0) ----
  if (side == 0) { MMLDS() }
  else { POSC(0, 0) }
  __syncthreads();
  // ---- dbeta(1): B: MM_B^dec(1) ; A: GATE_A(1) + POSC_B(0) ----
  if (side == 1) { MMLDS() }
  else { GATEC(0) POSC(0, 1) }
  __syncthreads();

  // ---- decoder d = 2..11 ----
#pragma unroll 1
  for (int d = 2; d < PRED_LEN; ++d) {
    if (side == 0) { MMLDS() }
    else { GATEC(0) POSC(d - 1, 0) }
    __syncthreads();
    if (side == 1) { MMLDS() }
    else { GATEC(0) POSC(d - 1, 1) }
    __syncthreads();
  }

  // ---- E1: B: GATE_B(11) + POSC_A(11) ----
  if (side == 1) { GATEC(0) POSC(PRED_LEN - 1, 0) }
  __syncthreads();
  // ---- E2: A: POSC_B(11) ----
  if (side == 0) { POSC(PRED_LEN - 1, 1) }
}

extern "C" void kernel_launch(void* const* d_in, const int* in_sizes, int n_in,
                              void* d_out, int out_size, void* d_ws, size_t ws_size,
                              hipStream_t stream) {
  const float* obs   = (const float*)d_in[0];
  const float* We    = (const float*)d_in[1];
  const float* be    = (const float*)d_in[2];
  const float* Wih_e = (const float*)d_in[3];
  const float* Whh_e = (const float*)d_in[4];
  const float* b_e   = (const float*)d_in[5];
  const float* Wd    = (const float*)d_in[6];
  const float* bd    = (const float*)d_in[7];
  const float* Wih_d = (const float*)d_in[8];
  const float* Whh_d = (const float*)d_in[9];
  const float* b_d   = (const float*)d_in[10];
  const float* Wo    = (const float*)d_in[11];
  const float* bo    = (const float*)d_in[12];
  float* out = (float*)d_out;

  unsigned short* wt_enc = (unsigned short*)d_ws;                 // 128 KB
  unsigned short* wt_dec = wt_enc + NZ * KWT;                     // +128 KB
  float* aux_enc = (float*)(wt_dec + NZ * KWT);                   // 6 KB
  float* aux_dec = aux_enc + 3 * NZ;                              // 2 KB

  // allow >64 KB dynamic LDS (148.5 KB); host-side config, not a stream op
  hipFuncSetAttribute((const void*)lstm_fused,
                      hipFuncAttributeMaxDynamicSharedMemorySize, SMEM_BYTES);

  hipLaunchKernelGGL(prep_weights, dim3(2 * NZ), dim3(64), 0, stream,
                     We, be, Wih_e, Whh_e, b_e, Wd, bd, Wih_d, Whh_d, b_d,
                     Wo, bo, wt_enc, wt_dec, aux_enc, aux_dec);
  hipLaunchKernelGGL(lstm_fused, dim3(BATCH / 64), dim3(1024), SMEM_BYTES,
                     stream, obs, wt_enc, wt_dec, aux_enc, aux_dec, Wo, bo, out);
}

// Round 10
// 528.863 us; speedup vs baseline: 1.4642x; 1.4642x over previous
//
#include <hip/hip_runtime.h>

// Round 10 = Round 9 + POSC weight-stride fix (pp_q*16, not pp_q*32 floats).
// Structure: 512 thr (8 waves, 2/SIMD, 256-reg budget, spill-free), 64 rows
// per block as two 32-row chunks interleaved: MM_X || GATE_Y per phase,
// 1 barrier/phase. VALU work moved into MFMA/prep:
//  - weights pre-scaled by -log2e (i,f,o) / -2log2e (g) -> gate phase starts
//    directly at exp2(acc).
//  - obs embedding + bias folded into an extra K=32 MFMA block: A2 row =
//    [px_hi,py_hi,1,px_lo,py_lo,0..] (exact hi/lo split), x-weights =
//    [s*wx, s*wy, s*bias, s*wx, s*wy]. Decoder A2 = [0,0,1,0,0].
//  - acc init via zero-quad C-input (no accvgpr init writes).
// h in LDS bf16 XOR-swizzled; c in f32 regs; decoder pos-path folded into
// Whh_d (pure LSTM, POS fire-and-forget).

#define OBS_LEN 8
#define PRED_LEN 12
#define BATCH 131072
#define HID 128
#define NZ 512
#define KWT 128
#define XK 32
#define A2S 40          // A2 row stride (u16) -> 2-way banks (free)

typedef float f32x4 __attribute__((ext_vector_type(4)));
typedef float f32x2 __attribute__((ext_vector_type(2)));
typedef unsigned short u16x8 __attribute__((ext_vector_type(8)));
typedef __bf16 bf16x8 __attribute__((ext_vector_type(8)));

#define K2F 1.4426950408889634f   // log2(e)

static __device__ __forceinline__ unsigned short cvt1(float f) {
  __bf16 b = (__bf16)f;
  return __builtin_bit_cast(unsigned short, b);
}
static __device__ __forceinline__ float bf2f(unsigned short h) {
  return __uint_as_float(((unsigned int)h) << 16);
}

// ---------------- prep ----------------
// Permuted col c: cg=c>>6, gate=(c>>4)&3, cl=c&15; unit=cg*16+cl; n=gate*128+unit.
// Scale s = -2*log2e for gate g (index 2), else -log2e.
// wt[c][k] = bf16(s * (Whh[k][n] (+ dec pos-fold)))            k<128
// xw[c][0..4] = bf16(s*{wx, wy, bias, wx, wy}); [5..31]=0
__global__ void prep_weights(const float* __restrict__ We,   const float* __restrict__ be,
                             const float* __restrict__ Wih_e,const float* __restrict__ Whh_e,
                             const float* __restrict__ b_e,
                             const float* __restrict__ Wd,   const float* __restrict__ bd,
                             const float* __restrict__ Wih_d,const float* __restrict__ Whh_d,
                             const float* __restrict__ b_d,
                             const float* __restrict__ Wo,   const float* __restrict__ bo,
                             unsigned short* __restrict__ wt_enc,
                             unsigned short* __restrict__ wt_dec,
                             unsigned short* __restrict__ xw_enc,
                             unsigned short* __restrict__ xw_dec) {
  const int c = blockIdx.x & (NZ - 1);
  const bool dec = blockIdx.x >= NZ;
  const int cg = c >> 6, gate = (c >> 4) & 3, cl = c & 15;
  const int unit = cg * 16 + cl;
  const int n = gate * HID + unit;
  const float s = (gate == 2) ? (-2.f * K2F) : (-K2F);

  const float* Whh = dec ? Whh_d : Whh_e;
  const float* Wih = dec ? Wih_d : Wih_e;
  const float* Wem = dec ? Wd : We;
  const float* bem = dec ? bd : be;
  const float* bl  = dec ? b_d : b_e;
  unsigned short* wt = dec ? wt_dec : wt_enc;
  unsigned short* xw = dec ? xw_dec : xw_enc;

  float wx = 0.f, wy = 0.f;
  for (int e = 0; e < HID; ++e) {
    wx += Wem[e] * Wih[e * NZ + n];
    wy += Wem[HID + e] * Wih[e * NZ + n];
  }
  for (int k = threadIdx.x; k < KWT; k += 64) {
    float v = Whh[k * NZ + n];
    if (dec) v += Wo[k * 2] * wx + Wo[k * 2 + 1] * wy;
    wt[c * KWT + k] = cvt1(s * v);
  }
  if (threadIdx.x == 0) {
    float bb = bl[n];
    for (int e = 0; e < HID; ++e) bb += bem[e] * Wih[e * NZ + n];
    if (dec) bb += bo[0] * wx + bo[1] * wy;
    unsigned short* xr = xw + c * XK;
    for (int k = 5; k < XK; ++k) xr[k] = 0;
    if (dec) {
      xr[0] = 0; xr[1] = 0; xr[2] = cvt1(s * bb); xr[3] = 0; xr[4] = 0;
    } else {
      xr[0] = cvt1(s * wx); xr[1] = cvt1(s * wy); xr[2] = cvt1(s * bb);
      xr[3] = xr[0]; xr[4] = xr[1];
    }
  }
}

// ---------------- main fused kernel ----------------
// MFMA 16x16x32 bf16 (HW-verified r1-r8):
//  A/B frag: row/col = lane&15, k = 32kc + (lane>>4)*8 + j
//  C/D: col = lane&15, row = (lane>>4)*4 + reg
// hL swizzle (r7-verified): elem(r,k) = r*128 + (((k>>3)^(r&7))<<3) + (k&7)

#define MFMA(A, B, C)                                                          \
  __builtin_amdgcn_mfma_f32_16x16x32_bf16(                                     \
      __builtin_bit_cast(bf16x8, (A)), __builtin_bit_cast(bf16x8, (B)), (C),   \
      0, 0, 0)

#define EXP4(D, S)                                                             \
  { f32x4 _s = (S);                                                            \
    D[0] = __builtin_amdgcn_exp2f(_s[0]); D[1] = __builtin_amdgcn_exp2f(_s[1]);\
    D[2] = __builtin_amdgcn_exp2f(_s[2]); D[3] = __builtin_amdgcn_exp2f(_s[3]); }
#define RCP4(D, S)                                                             \
  { f32x4 _r = (S);                                                            \
    D[0] = __builtin_amdgcn_rcpf(_r[0]); D[1] = __builtin_amdgcn_rcpf(_r[1]);  \
    D[2] = __builtin_amdgcn_rcpf(_r[2]); D[3] = __builtin_amdgcn_rcpf(_r[3]); }

#define LOADW(WT, XW)                                                          \
  { _Pragma("unroll")                                                          \
    for (int kc = 0; kc < 4; ++kc) {                                           \
      _Pragma("unroll")                                                        \
      for (int g = 0; g < 4; ++g)                                              \
        bfr[kc][g] =                                                           \
            *(const u16x8*)&(WT)[(cg * 64 + g * 16 + l15) * KWT + kc * 32 +    \
                                 l4 * 8];                                      \
    }                                                                          \
    _Pragma("unroll")                                                          \
    for (int g = 0; g < 4; ++g)                                                \
      xfr[g] = *(const u16x8*)&(XW)[(cg * 64 + g * 16 + l15) * XK + l4 * 8]; }

// full matmul for chunk X: x-block (K=32, zero-C) then h (K=128)
#define MMX(ACC, X)                                                            \
  { u16x8 mm_a2a = *(const u16x8*)&A2[(X)*32 * A2S + l15 * A2S + l4 * 8];      \
    u16x8 mm_a2b =                                                             \
        *(const u16x8*)&A2[(X)*32 * A2S + (16 + l15) * A2S + l4 * 8];          \
    _Pragma("unroll")                                                          \
    for (int g = 0; g < 4; ++g) {                                              \
      ACC[0][g] = MFMA(mm_a2a, xfr[g], ZROV);                                  \
      ACC[1][g] = MFMA(mm_a2b, xfr[g], ZROV);                                  \
    }                                                                          \
    _Pragma("unroll")                                                          \
    for (int kc = 0; kc < 4; ++kc) {                                           \
      const int mm_g = (((kc * 4 + l4) ^ (l15 & 7)) << 3);                     \
      u16x8 mm_a0 = *(const u16x8*)&hL[(X)*4096 + l15 * 128 + mm_g];           \
      u16x8 mm_a1 = *(const u16x8*)&hL[(X)*4096 + (16 + l15) * 128 + mm_g];    \
      _Pragma("unroll")                                                        \
      for (int g = 0; g < 4; ++g) {                                            \
        ACC[0][g] = MFMA(mm_a0, bfr[kc][g], ACC[0][g]);                        \
        ACC[1][g] = MFMA(mm_a1, bfr[kc][g], ACC[1][g]);                        \
      } } }

// gate for chunk X: acc already = scaled z (incl obs fold + bias)
#define GATEC(ACC, CRR, X)                                                     \
  { _Pragma("unroll")                                                          \
    for (int m = 0; m < 2; ++m) {                                              \
      f32x4 g_eB, g_eA, g_eG, g_eO;                                            \
      EXP4(g_eB, ACC[m][0]) EXP4(g_eA, ACC[m][1])                              \
      EXP4(g_eG, ACC[m][2]) EXP4(g_eO, ACC[m][3])                              \
      f32x4 g_a1 = 1.f + g_eA, g_b1 = 1.f + g_eB, g_g1 = 1.f + g_eG;           \
      f32x4 g_bg = g_b1 * g_g1;                                                \
      f32x4 g_rd; RCP4(g_rd, g_a1 * g_bg)                                      \
      f32x4 g_cv = (CRR[m] * g_bg + (1.f - g_eG) * g_a1) * g_rd;               \
      CRR[m] = g_cv;                                                           \
      f32x4 g_eC; EXP4(g_eC, g_cv * (-2.f * K2F))                              \
      f32x4 g_rh; RCP4(g_rh, (1.f + g_eO) * (1.f + g_eC))                      \
      f32x4 g_hv = (1.f - g_eC) * g_rh;                                        \
      const int g_R0 = 16 * m + l4 * 4;                                        \
      _Pragma("unroll")                                                        \
      for (int r = 0; r < 4; ++r)                                              \
        hL[(X)*4096 + (g_R0 + r) * 128 + ((uh ^ ((g_R0 + r) & 7)) << 3) +      \
           ul] = cvt1(g_hv[r]);                                                \
    } }

// pos = h @ Wo + bo, fire-and-forget. 16 thr/row over 32 rows of chunk X.
// Each thread covers 8 units -> weight slice starts at pp_q*8 units =
// pp_q*16 floats (r9 bug: had pp_q*32).
#define POSC(S, X)                                                             \
  { const int pp_r = tid >> 4, pp_q = tid & 15;                                \
    u16x8 pp_h = *(const u16x8*)&hL[(X)*4096 + pp_r * 128 +                    \
                                    ((pp_q ^ (pp_r & 7)) << 3)];               \
    const float* pp_w = WoL + pp_q * 16;                                       \
    f32x4 pp_w0 = *(const f32x4*)pp_w;                                         \
    f32x4 pp_w1 = *(const f32x4*)(pp_w + 4);                                   \
    f32x4 pp_w2 = *(const f32x4*)(pp_w + 8);                                   \
    f32x4 pp_w3 = *(const f32x4*)(pp_w + 12);                                  \
    f32x2 pp_s = (f32x2){0.f, 0.f};                                            \
    pp_s += bf2f(pp_h[0]) * (f32x2){pp_w0[0], pp_w0[1]};                       \
    pp_s += bf2f(pp_h[1]) * (f32x2){pp_w0[2], pp_w0[3]};                       \
    pp_s += bf2f(pp_h[2]) * (f32x2){pp_w1[0], pp_w1[1]};                       \
    pp_s += bf2f(pp_h[3]) * (f32x2){pp_w1[2], pp_w1[3]};                       \
    pp_s += bf2f(pp_h[4]) * (f32x2){pp_w2[0], pp_w2[1]};                       \
    pp_s += bf2f(pp_h[5]) * (f32x2){pp_w2[2], pp_w2[3]};                       \
    pp_s += bf2f(pp_h[6]) * (f32x2){pp_w3[0], pp_w3[1]};                       \
    pp_s += bf2f(pp_h[7]) * (f32x2){pp_w3[2], pp_w3[3]};                       \
    pp_s[0] += __shfl_xor(pp_s[0], 1); pp_s[1] += __shfl_xor(pp_s[1], 1);      \
    pp_s[0] += __shfl_xor(pp_s[0], 2); pp_s[1] += __shfl_xor(pp_s[1], 2);      \
    pp_s[0] += __shfl_xor(pp_s[0], 4); pp_s[1] += __shfl_xor(pp_s[1], 4);      \
    pp_s[0] += __shfl_xor(pp_s[0], 8); pp_s[1] += __shfl_xor(pp_s[1], 8);      \
    if (pp_q == 0) {                                                           \
      float2 pp_o; pp_o.x = pp_s[0] + bo0; pp_o.y = pp_s[1] + bo1;             \
      ((float2*)out)[(size_t)(S)*BATCH + row0 + (X)*32 + pp_r] = pp_o;         \
    } }

// stage encoder A2 for chunk X, step T (exact hi/lo split)
#define STAGE_OBS_A2(T, X)                                                     \
  if (tid < 32) {                                                              \
    float2 so_p =                                                              \
        ((const float2*)obs)[(size_t)(T)*BATCH + row0 + (X)*32 + tid];         \
    unsigned short so_x = cvt1(so_p.x), so_y = cvt1(so_p.y);                   \
    unsigned short* so_r = &A2[(X)*32 * A2S + tid * A2S];                      \
    so_r[0] = so_x; so_r[1] = so_y; so_r[2] = 0x3F80u;                         \
    so_r[3] = cvt1(so_p.x - bf2f(so_x));                                       \
    so_r[4] = cvt1(so_p.y - bf2f(so_y));                                       \
  }

// decoder A2 constants for chunk X
#define STAGE_DEC_A2(X)                                                        \
  if (tid < 32) {                                                              \
    unsigned short* sd_r = &A2[(X)*32 * A2S + tid * A2S];                      \
    sd_r[0] = 0; sd_r[1] = 0; sd_r[2] = 0x3F80u; sd_r[3] = 0; sd_r[4] = 0;     \
  }

__global__ __launch_bounds__(512, 2) void lstm_fused(
    const float* __restrict__ obs,
    const unsigned short* __restrict__ wt_enc,
    const unsigned short* __restrict__ wt_dec,
    const unsigned short* __restrict__ xw_enc,
    const unsigned short* __restrict__ xw_dec,
    const float* __restrict__ Wo, const float* __restrict__ bo,
    float* __restrict__ out) {
  __shared__ unsigned short hL[2 * 32 * 128];   // 16 KB, XOR-swizzled
  __shared__ unsigned short A2[2 * 32 * A2S];   // 5 KB
  __shared__ float WoL[HID * 2];                // 1 KB

  const int tid = threadIdx.x;
  const int lane = tid & 63;
  const int cg = tid >> 6;          // wave 0..7 -> cols [64cg, 64cg+64)
  const int l15 = lane & 15;
  const int l4 = lane >> 4;
  const int row0 = blockIdx.x * 64;
  const int u = cg * 16 + l15, uh = u >> 3, ul = u & 7;
  const float bo0 = bo[0], bo1 = bo[1];
  const f32x4 ZROV = {0.f, 0.f, 0.f, 0.f};

  // ---- P0a: zero hL + A2, load WoL + weights ----
  {
    u16x8 z8 = (u16x8){0, 0, 0, 0, 0, 0, 0, 0};
    *(u16x8*)&hL[tid * 8] = z8;                      // 512*8 = 4096
    *(u16x8*)&hL[4096 + tid * 8] = z8;
    unsigned short* az = &A2[tid * 5];               // 512*5 = 2560 = 2*32*40
    az[0] = 0; az[1] = 0; az[2] = 0; az[3] = 0; az[4] = 0;
  }
  if (tid < HID) { WoL[tid * 2] = Wo[tid * 2]; WoL[tid * 2 + 1] = Wo[tid * 2 + 1]; }

  u16x8 bfr[4][4], xfr[4];          // persistent weights: 80 regs
  LOADW(wt_enc, xw_enc);

  f32x4 accA[2][4], accB[2][4];
  f32x4 crrA[2], crrB[2];
  crrA[0] = crrA[1] = ZROV;
  crrB[0] = crrB[1] = ZROV;
  __syncthreads();

  // ---- P0b: stage A2_A(0). (A2_B(0) is staged in alpha(0).) ----
  STAGE_OBS_A2(0, 0)
  __syncthreads();

  // ---- encoder t = 0..7: alpha: MM_A(t)+GATE_B(t-1)+stageA2_B(t);
  //                         beta:  MM_B(t)+GATE_A(t)+stageA2_A(t+1) ----
#pragma unroll 1
  for (int t = 0; t < OBS_LEN; ++t) {
    MMX(accA, 0)
    if (t > 0) { GATEC(accB, crrB, 1) }
    STAGE_OBS_A2(t, 1)
    __syncthreads();
    MMX(accB, 1)
    GATEC(accA, crrA, 0)
    if (t + 1 < OBS_LEN) { STAGE_OBS_A2(t + 1, 0) }
    else { STAGE_DEC_A2(0) }
    __syncthreads();
  }

  // ---- transition: decoder weights; reset c for chunk A ----
  LOADW(wt_dec, xw_dec);
  crrA[0] = crrA[1] = ZROV;

  // alpha_d(1): MM_A^dec(1) + GATE_B(7,enc) + POSC_A(0) + stage A2_B dec
  MMX(accA, 0)
  GATEC(accB, crrB, 1)
  POSC(0, 0)
  STAGE_DEC_A2(1)
  __syncthreads();
  crrB[0] = crrB[1] = ZROV;

  // beta_d(1): MM_B^dec(1) + GATE_A^dec(1) + POSC_B(0)
  MMX(accB, 1)
  GATEC(accA, crrA, 0)
  POSC(0, 1)
  __syncthreads();

  // ---- decoder d = 2..11 ----
#pragma unroll 1
  for (int d = 2; d < PRED_LEN; ++d) {
    MMX(accA, 0)
    GATEC(accB, crrB, 1)
    POSC(d - 1, 0)
    __syncthreads();
    MMX(accB, 1)
    GATEC(accA, crrA, 0)
    POSC(d - 1, 1)
    __syncthreads();
  }

  // ---- epilogue ----
  GATEC(accB, crrB, 1)
  POSC(PRED_LEN - 1, 0)
  __syncthreads();
  POSC(PRED_LEN - 1, 1)
}

extern "C" void kernel_launch(void* const* d_in, const int* in_sizes, int n_in,
                              void* d_out, int out_size, void* d_ws, size_t ws_size,
                              hipStream_t stream) {
  const float* obs   = (const float*)d_in[0];
  const float* We    = (const float*)d_in[1];
  const float* be    = (const float*)d_in[2];
  const float* Wih_e = (const float*)d_in[3];
  const float* Whh_e = (const float*)d_in[4];
  const float* b_e   = (const float*)d_in[5];
  const float* Wd    = (const float*)d_in[6];
  const float* bd    = (const float*)d_in[7];
  const float* Wih_d = (const float*)d_in[8];
  const float* Whh_d = (const float*)d_in[9];
  const float* b_d   = (const float*)d_in[10];
  const float* Wo    = (const float*)d_in[11];
  const float* bo    = (const float*)d_in[12];
  float* out = (float*)d_out;

  unsigned short* wt_enc = (unsigned short*)d_ws;                 // 128 KB
  unsigned short* wt_dec = wt_enc + NZ * KWT;                     // +128 KB
  unsigned short* xw_enc = wt_dec + NZ * KWT;                     // +32 KB
  unsigned short* xw_dec = xw_enc + NZ * XK;                      // +32 KB

  hipLaunchKernelGGL(prep_weights, dim3(2 * NZ), dim3(64), 0, stream,
                     We, be, Wih_e, Whh_e, b_e, Wd, bd, Wih_d, Whh_d, b_d,
                     Wo, bo, wt_enc, wt_dec, xw_enc, xw_dec);
  hipLaunchKernelGGL(lstm_fused, dim3(BATCH / 64), dim3(512), 0, stream,
                     obs, wt_enc, wt_dec, xw_enc, xw_dec, Wo, bo, out);
}

// Round 11
// 521.129 us; speedup vs baseline: 1.4860x; 1.0148x over previous
//
#include <hip/hip_runtime.h>

// Round 11 = Round 10 + 4-bit LDS swizzle fix.
// r10's hL swizzle used (row&7) over 16 slots/row: each 16-lane quarter-group
// hit only 8 distinct 16B slots (2 rows/slot, same banks since 256B row
// stride == 0 mod 128B bank cycle) -> systematic bank conflicts on every
// MMX A-read (SQ_LDS_BANK_CONFLICT 4.4e7). Fix: slot = (k>>3) ^ (row&15),
// a bijection on 4 bits -> every quarter-group spans all 16 slots.
// Everything else identical to r10: 512 thr (8 waves, 2/SIMD, spill-free),
// two 32-row chunks interleaved (MM_X || GATE_Y per phase, 1 barrier/phase),
// weights pre-scaled by -log2e / -2log2e, obs+bias folded as K=32 MFMA block,
// decoder pos-path folded into Whh_d, c in f32 regs.

#define OBS_LEN 8
#define PRED_LEN 12
#define BATCH 131072
#define HID 128
#define NZ 512
#define KWT 128
#define XK 32
#define A2S 40          // A2 row stride (u16): 80B -> 2-way banks (free)

typedef float f32x4 __attribute__((ext_vector_type(4)));
typedef float f32x2 __attribute__((ext_vector_type(2)));
typedef unsigned short u16x8 __attribute__((ext_vector_type(8)));
typedef __bf16 bf16x8 __attribute__((ext_vector_type(8)));

#define K2F 1.4426950408889634f   // log2(e)

static __device__ __forceinline__ unsigned short cvt1(float f) {
  __bf16 b = (__bf16)f;
  return __builtin_bit_cast(unsigned short, b);
}
static __device__ __forceinline__ float bf2f(unsigned short h) {
  return __uint_as_float(((unsigned int)h) << 16);
}

// ---------------- prep (r10-verified, unchanged) ----------------
// Permuted col c: cg=c>>6, gate=(c>>4)&3, cl=c&15; unit=cg*16+cl; n=gate*128+unit.
// Scale s = -2*log2e for gate g (index 2), else -log2e.
__global__ void prep_weights(const float* __restrict__ We,   const float* __restrict__ be,
                             const float* __restrict__ Wih_e,const float* __restrict__ Whh_e,
                             const float* __restrict__ b_e,
                             const float* __restrict__ Wd,   const float* __restrict__ bd,
                             const float* __restrict__ Wih_d,const float* __restrict__ Whh_d,
                             const float* __restrict__ b_d,
                             const float* __restrict__ Wo,   const float* __restrict__ bo,
                             unsigned short* __restrict__ wt_enc,
                             unsigned short* __restrict__ wt_dec,
                             unsigned short* __restrict__ xw_enc,
                             unsigned short* __restrict__ xw_dec) {
  const int c = blockIdx.x & (NZ - 1);
  const bool dec = blockIdx.x >= NZ;
  const int cg = c >> 6, gate = (c >> 4) & 3, cl = c & 15;
  const int unit = cg * 16 + cl;
  const int n = gate * HID + unit;
  const float s = (gate == 2) ? (-2.f * K2F) : (-K2F);

  const float* Whh = dec ? Whh_d : Whh_e;
  const float* Wih = dec ? Wih_d : Wih_e;
  const float* Wem = dec ? Wd : We;
  const float* bem = dec ? bd : be;
  const float* bl  = dec ? b_d : b_e;
  unsigned short* wt = dec ? wt_dec : wt_enc;
  unsigned short* xw = dec ? xw_dec : xw_enc;

  float wx = 0.f, wy = 0.f;
  for (int e = 0; e < HID; ++e) {
    wx += Wem[e] * Wih[e * NZ + n];
    wy += Wem[HID + e] * Wih[e * NZ + n];
  }
  for (int k = threadIdx.x; k < KWT; k += 64) {
    float v = Whh[k * NZ + n];
    if (dec) v += Wo[k * 2] * wx + Wo[k * 2 + 1] * wy;
    wt[c * KWT + k] = cvt1(s * v);
  }
  if (threadIdx.x == 0) {
    float bb = bl[n];
    for (int e = 0; e < HID; ++e) bb += bem[e] * Wih[e * NZ + n];
    if (dec) bb += bo[0] * wx + bo[1] * wy;
    unsigned short* xr = xw + c * XK;
    for (int k = 5; k < XK; ++k) xr[k] = 0;
    if (dec) {
      xr[0] = 0; xr[1] = 0; xr[2] = cvt1(s * bb); xr[3] = 0; xr[4] = 0;
    } else {
      xr[0] = cvt1(s * wx); xr[1] = cvt1(s * wy); xr[2] = cvt1(s * bb);
      xr[3] = xr[0]; xr[4] = xr[1];
    }
  }
}

// ---------------- main fused kernel ----------------
// MFMA 16x16x32 bf16 (HW-verified r1-r10):
//  A/B frag: row/col = lane&15, k = 32kc + (lane>>4)*8 + j
//  C/D: col = lane&15, row = (lane>>4)*4 + reg
// hL swizzle (4-bit, bijective): elem(r,k) = r*128 + (((k>>3)^(r&15))<<3)+(k&7)

#define MFMA(A, B, C)                                                          \
  __builtin_amdgcn_mfma_f32_16x16x32_bf16(                                     \
      __builtin_bit_cast(bf16x8, (A)), __builtin_bit_cast(bf16x8, (B)), (C),   \
      0, 0, 0)

#define EXP4(D, S)                                                             \
  { f32x4 _s = (S);                                                            \
    D[0] = __builtin_amdgcn_exp2f(_s[0]); D[1] = __builtin_amdgcn_exp2f(_s[1]);\
    D[2] = __builtin_amdgcn_exp2f(_s[2]); D[3] = __builtin_amdgcn_exp2f(_s[3]); }
#define RCP4(D, S)                                                             \
  { f32x4 _r = (S);                                                            \
    D[0] = __builtin_amdgcn_rcpf(_r[0]); D[1] = __builtin_amdgcn_rcpf(_r[1]);  \
    D[2] = __builtin_amdgcn_rcpf(_r[2]); D[3] = __builtin_amdgcn_rcpf(_r[3]); }

#define LOADW(WT, XW)                                                          \
  { _Pragma("unroll")                                                          \
    for (int kc = 0; kc < 4; ++kc) {                                           \
      _Pragma("unroll")                                                        \
      for (int g = 0; g < 4; ++g)                                              \
        bfr[kc][g] =                                                           \
            *(const u16x8*)&(WT)[(cg * 64 + g * 16 + l15) * KWT + kc * 32 +    \
                                 l4 * 8];                                      \
    }                                                                          \
    _Pragma("unroll")                                                          \
    for (int g = 0; g < 4; ++g)                                                \
      xfr[g] = *(const u16x8*)&(XW)[(cg * 64 + g * 16 + l15) * XK + l4 * 8]; }

// full matmul for chunk X: x-block (K=32, zero-C) then h (K=128).
// A-read slot = (kc*4+l4) ^ l15  (row l15 / 16+l15: (row&15)==l15 both).
#define MMX(ACC, X)                                                            \
  { u16x8 mm_a2a = *(const u16x8*)&A2[(X)*32 * A2S + l15 * A2S + l4 * 8];      \
    u16x8 mm_a2b =                                                             \
        *(const u16x8*)&A2[(X)*32 * A2S + (16 + l15) * A2S + l4 * 8];          \
    _Pragma("unroll")                                                          \
    for (int g = 0; g < 4; ++g) {                                              \
      ACC[0][g] = MFMA(mm_a2a, xfr[g], ZROV);                                  \
      ACC[1][g] = MFMA(mm_a2b, xfr[g], ZROV);                                  \
    }                                                                          \
    _Pragma("unroll")                                                          \
    for (int kc = 0; kc < 4; ++kc) {                                           \
      const int mm_g = (((kc * 4 + l4) ^ l15) << 3);                           \
      u16x8 mm_a0 = *(const u16x8*)&hL[(X)*4096 + l15 * 128 + mm_g];           \
      u16x8 mm_a1 = *(const u16x8*)&hL[(X)*4096 + (16 + l15) * 128 + mm_g];    \
      _Pragma("unroll")                                                        \
      for (int g = 0; g < 4; ++g) {                                            \
        ACC[0][g] = MFMA(mm_a0, bfr[kc][g], ACC[0][g]);                        \
        ACC[1][g] = MFMA(mm_a1, bfr[kc][g], ACC[1][g]);                        \
      } } }

// gate for chunk X: acc already = scaled z (incl obs fold + bias)
#define GATEC(ACC, CRR, X)                                                     \
  { _Pragma("unroll")                                                          \
    for (int m = 0; m < 2; ++m) {                                              \
      f32x4 g_eB, g_eA, g_eG, g_eO;                                            \
      EXP4(g_eB, ACC[m][0]) EXP4(g_eA, ACC[m][1])                              \
      EXP4(g_eG, ACC[m][2]) EXP4(g_eO, ACC[m][3])                              \
      f32x4 g_a1 = 1.f + g_eA, g_b1 = 1.f + g_eB, g_g1 = 1.f + g_eG;           \
      f32x4 g_bg = g_b1 * g_g1;                                                \
      f32x4 g_rd; RCP4(g_rd, g_a1 * g_bg)                                      \
      f32x4 g_cv = (CRR[m] * g_bg + (1.f - g_eG) * g_a1) * g_rd;               \
      CRR[m] = g_cv;                                                           \
      f32x4 g_eC; EXP4(g_eC, g_cv * (-2.f * K2F))                              \
      f32x4 g_rh; RCP4(g_rh, (1.f + g_eO) * (1.f + g_eC))                      \
      f32x4 g_hv = (1.f - g_eC) * g_rh;                                        \
      const int g_R0 = 16 * m + l4 * 4;                                        \
      _Pragma("unroll")                                                        \
      for (int r = 0; r < 4; ++r)                                              \
        hL[(X)*4096 + (g_R0 + r) * 128 +                                       \
           ((uh ^ ((g_R0 + r) & 15)) << 3) + ul] = cvt1(g_hv[r]);              \
    } }

// pos = h @ Wo + bo, fire-and-forget. 16 thr/row over 32 rows of chunk X.
#define POSC(S, X)                                                             \
  { const int pp_r = tid >> 4, pp_q = tid & 15;                                \
    u16x8 pp_h = *(const u16x8*)&hL[(X)*4096 + pp_r * 128 +                    \
                                    ((pp_q ^ (pp_r & 15)) << 3)];              \
    const float* pp_w = WoL + pp_q * 16;                                       \
    f32x4 pp_w0 = *(const f32x4*)pp_w;                                         \
    f32x4 pp_w1 = *(const f32x4*)(pp_w + 4);                                   \
    f32x4 pp_w2 = *(const f32x4*)(pp_w + 8);                                   \
    f32x4 pp_w3 = *(const f32x4*)(pp_w + 12);                                  \
    f32x2 pp_s = (f32x2){0.f, 0.f};                                            \
    pp_s += bf2f(pp_h[0]) * (f32x2){pp_w0[0], pp_w0[1]};                       \
    pp_s += bf2f(pp_h[1]) * (f32x2){pp_w0[2], pp_w0[3]};                       \
    pp_s += bf2f(pp_h[2]) * (f32x2){pp_w1[0], pp_w1[1]};                       \
    pp_s += bf2f(pp_h[3]) * (f32x2){pp_w1[2], pp_w1[3]};                       \
    pp_s += bf2f(pp_h[4]) * (f32x2){pp_w2[0], pp_w2[1]};                       \
    pp_s += bf2f(pp_h[5]) * (f32x2){pp_w2[2], pp_w2[3]};                       \
    pp_s += bf2f(pp_h[6]) * (f32x2){pp_w3[0], pp_w3[1]};                       \
    pp_s += bf2f(pp_h[7]) * (f32x2){pp_w3[2], pp_w3[3]};                       \
    pp_s[0] += __shfl_xor(pp_s[0], 1); pp_s[1] += __shfl_xor(pp_s[1], 1);      \
    pp_s[0] += __shfl_xor(pp_s[0], 2); pp_s[1] += __shfl_xor(pp_s[1], 2);      \
    pp_s[0] += __shfl_xor(pp_s[0], 4); pp_s[1] += __shfl_xor(pp_s[1], 4);      \
    pp_s[0] += __shfl_xor(pp_s[0], 8); pp_s[1] += __shfl_xor(pp_s[1], 8);      \
    if (pp_q == 0) {                                                           \
      float2 pp_o; pp_o.x = pp_s[0] + bo0; pp_o.y = pp_s[1] + bo1;             \
      ((float2*)out)[(size_t)(S)*BATCH + row0 + (X)*32 + pp_r] = pp_o;         \
    } }

// stage encoder A2 for chunk X, step T (exact hi/lo split)
#define STAGE_OBS_A2(T, X)                                                     \
  if (tid < 32) {                                                              \
    float2 so_p =                                                              \
        ((const float2*)obs)[(size_t)(T)*BATCH + row0 + (X)*32 + tid];         \
    unsigned short so_x = cvt1(so_p.x), so_y = cvt1(so_p.y);                   \
    unsigned short* so_r = &A2[(X)*32 * A2S + tid * A2S];                      \
    so_r[0] = so_x; so_r[1] = so_y; so_r[2] = 0x3F80u;                         \
    so_r[3] = cvt1(so_p.x - bf2f(so_x));                                       \
    so_r[4] = cvt1(so_p.y - bf2f(so_y));                                       \
  }

// decoder A2 constants for chunk X
#define STAGE_DEC_A2(X)                                                        \
  if (tid < 32) {                                                              \
    unsigned short* sd_r = &A2[(X)*32 * A2S + tid * A2S];                      \
    sd_r[0] = 0; sd_r[1] = 0; sd_r[2] = 0x3F80u; sd_r[3] = 0; sd_r[4] = 0;     \
  }

__global__ __launch_bounds__(512, 2) void lstm_fused(
    const float* __restrict__ obs,
    const unsigned short* __restrict__ wt_enc,
    const unsigned short* __restrict__ wt_dec,
    const unsigned short* __restrict__ xw_enc,
    const unsigned short* __restrict__ xw_dec,
    const float* __restrict__ Wo, const float* __restrict__ bo,
    float* __restrict__ out) {
  __shared__ unsigned short hL[2 * 32 * 128];   // 16 KB, 4-bit XOR-swizzled
  __shared__ unsigned short A2[2 * 32 * A2S];   // 5 KB
  __shared__ float WoL[HID * 2];                // 1 KB

  const int tid = threadIdx.x;
  const int lane = tid & 63;
  const int cg = tid >> 6;          // wave 0..7 -> cols [64cg, 64cg+64)
  const int l15 = lane & 15;
  const int l4 = lane >> 4;
  const int row0 = blockIdx.x * 64;
  const int u = cg * 16 + l15, uh = u >> 3, ul = u & 7;
  const float bo0 = bo[0], bo1 = bo[1];
  const f32x4 ZROV = {0.f, 0.f, 0.f, 0.f};

  // ---- P0a: zero hL + A2, load WoL + weights ----
  {
    u16x8 z8 = (u16x8){0, 0, 0, 0, 0, 0, 0, 0};
    *(u16x8*)&hL[tid * 8] = z8;                      // 512*8 = 4096
    *(u16x8*)&hL[4096 + tid * 8] = z8;
    unsigned short* az = &A2[tid * 5];               // 512*5 = 2560 = 2*32*40
    az[0] = 0; az[1] = 0; az[2] = 0; az[3] = 0; az[4] = 0;
  }
  if (tid < HID) { WoL[tid * 2] = Wo[tid * 2]; WoL[tid * 2 + 1] = Wo[tid * 2 + 1]; }

  u16x8 bfr[4][4], xfr[4];          // persistent weights: 80 regs
  LOADW(wt_enc, xw_enc);

  f32x4 accA[2][4], accB[2][4];
  f32x4 crrA[2], crrB[2];
  crrA[0] = crrA[1] = ZROV;
  crrB[0] = crrB[1] = ZROV;
  __syncthreads();

  // ---- P0b: stage A2_A(0). (A2_B(0) is staged in alpha(0).) ----
  STAGE_OBS_A2(0, 0)
  __syncthreads();

  // ---- encoder t = 0..7: alpha: MM_A(t)+GATE_B(t-1)+stageA2_B(t);
  //                         beta:  MM_B(t)+GATE_A(t)+stageA2_A(t+1) ----
#pragma unroll 1
  for (int t = 0; t < OBS_LEN; ++t) {
    MMX(accA, 0)
    if (t > 0) { GATEC(accB, crrB, 1) }
    STAGE_OBS_A2(t, 1)
    __syncthreads();
    MMX(accB, 1)
    GATEC(accA, crrA, 0)
    if (t + 1 < OBS_LEN) { STAGE_OBS_A2(t + 1, 0) }
    else { STAGE_DEC_A2(0) }
    __syncthreads();
  }

  // ---- transition: decoder weights; reset c for chunk A ----
  LOADW(wt_dec, xw_dec);
  crrA[0] = crrA[1] = ZROV;

  // alpha_d(1): MM_A^dec(1) + GATE_B(7,enc) + POSC_A(0) + stage A2_B dec
  MMX(accA, 0)
  GATEC(accB, crrB, 1)
  POSC(0, 0)
  STAGE_DEC_A2(1)
  __syncthreads();
  crrB[0] = crrB[1] = ZROV;

  // beta_d(1): MM_B^dec(1) + GATE_A^dec(1) + POSC_B(0)
  MMX(accB, 1)
  GATEC(accA, crrA, 0)
  POSC(0, 1)
  __syncthreads();

  // ---- decoder d = 2..11 ----
#pragma unroll 1
  for (int d = 2; d < PRED_LEN; ++d) {
    MMX(accA, 0)
    GATEC(accB, crrB, 1)
    POSC(d - 1, 0)
    __syncthreads();
    MMX(accB, 1)
    GATEC(accA, crrA, 0)
    POSC(d - 1, 1)
    __syncthreads();
  }

  // ---- epilogue ----
  GATEC(accB, crrB, 1)
  POSC(PRED_LEN - 1, 0)
  __syncthreads();
  POSC(PRED_LEN - 1, 1)
}

extern "C" void kernel_launch(void* const* d_in, const int* in_sizes, int n_in,
                              void* d_out, int out_size, void* d_ws, size_t ws_size,
                              hipStream_t stream) {
  const float* obs   = (const float*)d_in[0];
  const float* We    = (const float*)d_in[1];
  const float* be    = (const float*)d_in[2];
  const float* Wih_e = (const float*)d_in[3];
  const float* Whh_e = (const float*)d_in[4];
  const float* b_e   = (const float*)d_in[5];
  const float* Wd    = (const float*)d_in[6];
  const float* bd    = (const float*)d_in[7];
  const float* Wih_d = (const float*)d_in[8];
  const float* Whh_d = (const float*)d_in[9];
  const float* b_d   = (const float*)d_in[10];
  const float* Wo    = (const float*)d_in[11];
  const float* bo    = (const float*)d_in[12];
  float* out = (float*)d_out;

  unsigned short* wt_enc = (unsigned short*)d_ws;                 // 128 KB
  unsigned short* wt_dec = wt_enc + NZ * KWT;                     // +128 KB
  unsigned short* xw_enc = wt_dec + NZ * KWT;                     // +32 KB
  unsigned short* xw_dec = xw_enc + NZ * XK;                      // +32 KB

  hipLaunchKernelGGL(prep_weights, dim3(2 * NZ), dim3(64), 0, stream,
                     We, be, Wih_e, Whh_e, b_e, Wd, bd, Wih_d, Whh_d, b_d,
                     Wo, bo, wt_enc, wt_dec, xw_enc, xw_dec);
  hipLaunchKernelGGL(lstm_fused, dim3(BATCH / 64), dim3(512), 0, stream,
                     obs, wt_enc, wt_dec, xw_enc, xw_dec, Wo, bo, out);
}